// Round 6
// baseline (1033.349 us; speedup 1.0000x reference)
//
#include <hip/hip_runtime.h>
#include <math.h>

// Chamfer distance on MI355X (gfx950) via f16-split MFMA, two one-directional
// passes in a single kernel.  B=8, N=M=8192, fp32.
// out = concat(dist1[B*N], dist2[B*M]).
//
// Per direction: U[n,m] = |c_m|^2 - 2 q_n.c_m + 64, min over m -> dist partial.
// v_mfma_f32_32x32x16_f16 K-slots (f16-split of the fp32 expansion):
//   k0..2: qh*ch   k3..5: qh*cl   k6..8: ql*ch   k9,10: 1*sq_hi,1*sq_lo
//   k11: 1*64 (bias keeps U>0 so uint atomicMin is order-preserving)
// Dropped ql*cl term ~1e-6.  Fix-up: out[i] = max(min - 64 + |q_i|^2, 0).
//
// Fragment layouts (verified in R5 end-to-end): A[m=lane&31][k=(lane>>5)*8+j],
// B mirrored, C/D col=lane&31, row=(reg&3)+8*(reg>>2)+4*(lane>>5).
//
// Tiling: wave holds 4 A-frags (128 rows) + mm[4][16] running mins; block =
// 4 waves = 512 rows; B candidates staged in LDS (double-buffered 256-col
// chunks, register-prefetched) shared by all waves; per 2 col-tiles x 4
// row-tiles: 8 MFMA + 64 v_min3  ->  0.0156 VALU-cyc/pair.

typedef __attribute__((ext_vector_type(8)))  _Float16 half8;
typedef __attribute__((ext_vector_type(16))) float    floatx16;

#define NPTS  8192
#define BATCH 8
#define TOTAL (NPTS * BATCH)

#define RT_PER_WAVE 4                         // 4 row-tiles = 128 rows / wave
#define ROWS_BLOCK  (4 * 32 * RT_PER_WAVE)    // 512 rows / block (4 waves)
#define COL_SPLITS  2
#define COLS_BLOCK  (NPTS / COL_SPLITS)       // 4096 cols / block
#define CHUNK_TILES 8                         // 256 cols staged per chunk
#define CHUNK_COLS  (CHUNK_TILES * 32)
#define CHUNK_RECS  (CHUNK_TILES * 64)        // lo+hi records (float4 each)
#define NCHUNK      (COLS_BLOCK / CHUNK_COLS) // 16

// ---------------- prep: query-form and candidate-form operand records -------
__global__ __launch_bounds__(256) void chamfer_prep(
    const float* __restrict__ xyz1, const float* __restrict__ xyz2,
    half8* __restrict__ Qlo1, half8* __restrict__ Qhi1,
    half8* __restrict__ Clo1, half8* __restrict__ Chi1,
    half8* __restrict__ Qlo2, half8* __restrict__ Qhi2,
    half8* __restrict__ Clo2, half8* __restrict__ Chi2,
    float* __restrict__ sqArr)
{
    const int p = blockIdx.x * 256 + threadIdx.x;
    if (p >= TOTAL) return;
    const _Float16 ONE = (_Float16)1.0f, ZERO = (_Float16)0.0f;

    for (int s = 0; s < 2; ++s) {
        const float* src = s ? xyz2 : xyz1;
        const float x = src[3*p+0], y = src[3*p+1], z = src[3*p+2];
        const float sq = fmaf(x, x, fmaf(y, y, z * z));

        // query form: k0-2=qh, k3-5=qh, k6-8=ql, k9-11=1
        _Float16 hx=(_Float16)x, hy=(_Float16)y, hz=(_Float16)z;
        _Float16 lx=(_Float16)(x-(float)hx), ly=(_Float16)(y-(float)hy),
                 lz=(_Float16)(z-(float)hz);
        half8 qlo; qlo[0]=hx; qlo[1]=hy; qlo[2]=hz; qlo[3]=hx; qlo[4]=hy;
                   qlo[5]=hz; qlo[6]=lx; qlo[7]=ly;
        half8 qhi; qhi[0]=lz; qhi[1]=ONE; qhi[2]=ONE; qhi[3]=ONE;
                   qhi[4]=ZERO; qhi[5]=ZERO; qhi[6]=ZERO; qhi[7]=ZERO;

        // candidate form (v=-2c): k0-2=ch, k3-5=cl, k6-8=ch, k9=sqh,k10=sql,k11=64
        const float vx=-2.f*x, vy=-2.f*y, vz=-2.f*z;
        _Float16 cx=(_Float16)vx, cy=(_Float16)vy, cz=(_Float16)vz;
        _Float16 dx=(_Float16)(vx-(float)cx), dy=(_Float16)(vy-(float)cy),
                 dz=(_Float16)(vz-(float)cz);
        _Float16 sh=(_Float16)sq, sl=(_Float16)(sq-(float)sh);
        half8 clo; clo[0]=cx; clo[1]=cy; clo[2]=cz; clo[3]=dx; clo[4]=dy;
                   clo[5]=dz; clo[6]=cx; clo[7]=cy;
        half8 chi; chi[0]=cz; chi[1]=sh; chi[2]=sl; chi[3]=(_Float16)64.0f;
                   chi[4]=ZERO; chi[5]=ZERO; chi[6]=ZERO; chi[7]=ZERO;

        if (s == 0) { Qlo1[p]=qlo; Qhi1[p]=qhi; Clo1[p]=clo; Chi1[p]=chi;
                      sqArr[p] = sq; }
        else        { Qlo2[p]=qlo; Qhi2[p]=qhi; Clo2[p]=clo; Chi2[p]=chi;
                      sqArr[TOTAL + p] = sq; }
    }
}

// ---------------- main: one-directional MFMA min scan -----------------------
// grid = (NPTS/512, COL_SPLITS, 2*BATCH) = (16, 2, 16) = 512 blocks
__global__ __launch_bounds__(256, 2) void chamfer_mfma(
    const half8* __restrict__ Qlo1, const half8* __restrict__ Qhi1,
    const half8* __restrict__ Clo1, const half8* __restrict__ Chi1,
    const half8* __restrict__ Qlo2, const half8* __restrict__ Qhi2,
    const half8* __restrict__ Clo2, const half8* __restrict__ Chi2,
    float* __restrict__ out)
{
    const int zb   = blockIdx.z;
    const int dir  = zb >> 3;
    const int b    = zb & 7;
    const int tid  = threadIdx.x;
    const int lane = tid & 63, wave = tid >> 6;
    const int lm   = lane & 31;
    const bool hi  = lane >= 32;

    const half8 *Qlo, *Qhi, *Clo, *Chi; float* o;
    if (dir == 0) { Qlo=Qlo1; Qhi=Qhi1; Clo=Clo2; Chi=Chi2;
                    o = out + (size_t)b * NPTS; }
    else          { Qlo=Qlo2; Qhi=Qhi2; Clo=Clo1; Chi=Chi1;
                    o = out + (size_t)TOTAL + (size_t)b * NPTS; }

    __shared__ float4 sb[2][CHUNK_RECS];   // 2 x 8 KB double buffer

    // ---- A fragments: 4 row-tiles per wave, held in registers ----
    const int row_base = blockIdx.x * ROWS_BLOCK + wave * (RT_PER_WAVE * 32);
    const half8* Aarr = hi ? Qhi : Qlo;
    half8 a[RT_PER_WAVE];
#pragma unroll
    for (int rt = 0; rt < RT_PER_WAVE; ++rt)
        a[rt] = Aarr[(size_t)b * NPTS + row_base + rt * 32 + lm];

    float mm[RT_PER_WAVE][16];
#pragma unroll
    for (int rt = 0; rt < RT_PER_WAVE; ++rt)
#pragma unroll
        for (int r = 0; r < 16; ++r) mm[rt][r] = 3.0e38f;

    floatx16 zacc;
#pragma unroll
    for (int r = 0; r < 16; ++r) zacc[r] = 0.0f;

    const int col_base = blockIdx.y * COLS_BLOCK;
    const float4* gClo = (const float4*)(Clo + (size_t)b * NPTS);
    const float4* gChi = (const float4*)(Chi + (size_t)b * NPTS);

    // ---- stage chunk 0 (thread tid handles column col_base + tid) ----
    {
        const int src = col_base + tid;
        const int dst = (tid >> 5) * 64 + (tid & 31);
        sb[0][dst]      = gClo[src];
        sb[0][dst + 32] = gChi[src];
    }
    __syncthreads();

    const int boff = (hi ? 32 : 0) + lm;
    for (int c = 0; c < NCHUNK; ++c) {
        float4 n0, n1;
        if (c + 1 < NCHUNK) {                 // register prefetch of next chunk
            const int src = col_base + (c + 1) * CHUNK_COLS + tid;
            n0 = gClo[src];
            n1 = gChi[src];
        }
        const int cur = c & 1;
#pragma unroll
        for (int pt = 0; pt < CHUNK_TILES / 2; ++pt) {
            const half8 b0 = *(const half8*)&sb[cur][(2*pt)   * 64 + boff];
            const half8 b1 = *(const half8*)&sb[cur][(2*pt+1) * 64 + boff];
#pragma unroll
            for (int rt = 0; rt < RT_PER_WAVE; ++rt) {
                floatx16 d0 = __builtin_amdgcn_mfma_f32_32x32x16_f16(a[rt], b0, zacc, 0, 0, 0);
                floatx16 d1 = __builtin_amdgcn_mfma_f32_32x32x16_f16(a[rt], b1, zacc, 0, 0, 0);
#pragma unroll
                for (int r = 0; r < 16; ++r)
                    mm[rt][r] = fminf(fminf(d0[r], d1[r]), mm[rt][r]);  // v_min3
            }
        }
        if (c + 1 < NCHUNK) {
            const int dst = (tid >> 5) * 64 + (tid & 31);
            sb[1 - cur][dst]      = n0;
            sb[1 - cur][dst + 32] = n1;
            __syncthreads();
        }
    }

    // ---- epilogue: 32-lane min reduce per row, merge via uint atomicMin ----
#pragma unroll
    for (int rt = 0; rt < RT_PER_WAVE; ++rt)
#pragma unroll
        for (int r = 0; r < 16; ++r) {
            float v = mm[rt][r];
            v = fminf(v, __shfl_xor(v, 1));
            v = fminf(v, __shfl_xor(v, 2));
            v = fminf(v, __shfl_xor(v, 4));
            v = fminf(v, __shfl_xor(v, 8));
            v = fminf(v, __shfl_xor(v, 16));
            if (lm == 0) {
                const int rit = (r & 3) + 8 * (r >> 2) + (hi ? 4 : 0);
                atomicMin((unsigned*)(o + row_base + rt * 32 + rit),
                          __float_as_uint(v));
            }
        }
}

// ---------------- fix-up: un-bias, add |q|^2, clamp -------------------------
__global__ __launch_bounds__(256) void chamfer_fix(
    float* __restrict__ out, const float* __restrict__ sqArr)
{
    const int i = blockIdx.x * 256 + threadIdx.x;
    if (i < 2 * TOTAL) out[i] = fmaxf(out[i] - 64.0f + sqArr[i], 0.0f);
}

// ---------------- fallback (R2 VALU kernel, if ws too small) ----------------
#define FB_BLOCK 256
#define FB_Q 8
#define FB_QB (FB_BLOCK * FB_Q)
#define FB_CT 256
__global__ __launch_bounds__(FB_BLOCK, 8) void chamfer_valu(
    const float* __restrict__ xyz1, const float* __restrict__ xyz2,
    float* __restrict__ out, int B, int N, int M)
{
    const int z = blockIdx.z, dir = z / B, b = z % B;
    const float* qp; const float* cp; float* o; int Nq, Nc;
    if (dir == 0) { qp = xyz1 + (size_t)b*N*3; cp = xyz2 + (size_t)b*M*3;
                    o = out + (size_t)b*N; Nq = N; Nc = M; }
    else          { qp = xyz2 + (size_t)b*M*3; cp = xyz1 + (size_t)b*N*3;
                    o = out + (size_t)B*N + (size_t)b*M; Nq = M; Nc = N; }
    __shared__ float4 sc[FB_CT];
    const int c0 = blockIdx.y * FB_CT;
    for (int i = threadIdx.x; i < FB_CT; i += FB_BLOCK) {
        const int j = c0 + i;
        float x=0,y=0,zz=0,sq=3.0e38f;
        if (j < Nc) { x=cp[3*j]; y=cp[3*j+1]; zz=cp[3*j+2]; sq=x*x+y*y+zz*zz; }
        sc[i] = make_float4(-2.f*x, -2.f*y, -2.f*zz, sq);
    }
    __syncthreads();
    const int n0 = blockIdx.x * FB_QB + threadIdx.x;
    float qx[FB_Q], qy[FB_Q], qz[FB_Q], mm[FB_Q];
#pragma unroll
    for (int q = 0; q < FB_Q; ++q) {
        const int n = n0 + q*FB_BLOCK; float x=0,y=0,zz=0;
        if (n < Nq) { x=qp[3*n]; y=qp[3*n+1]; zz=qp[3*n+2]; }
        qx[q]=x; qy[q]=y; qz[q]=zz; mm[q]=3.0e38f;
    }
#pragma unroll 2
    for (int j = 0; j < FB_CT; j += 2) {
        const float4 ca = sc[j], cb = sc[j+1];
#pragma unroll
        for (int q = 0; q < FB_Q; ++q) {
            float t0 = fmaf(qx[q],ca.x,ca.w); t0=fmaf(qy[q],ca.y,t0); t0=fmaf(qz[q],ca.z,t0);
            float t1 = fmaf(qx[q],cb.x,cb.w); t1=fmaf(qy[q],cb.y,t1); t1=fmaf(qz[q],cb.z,t1);
            mm[q] = fminf(fminf(t0,t1), mm[q]);
        }
    }
#pragma unroll
    for (int q = 0; q < FB_Q; ++q) {
        const int n = n0 + q*FB_BLOCK;
        if (n < Nq) {
            float s = qx[q]*qx[q]; s=fmaf(qy[q],qy[q],s); s=fmaf(qz[q],qz[q],s);
            atomicMin((unsigned*)(o+n), __float_as_uint(fmaxf(s+mm[q],0.f)));
        }
    }
}

extern "C" void kernel_launch(void* const* d_in, const int* in_sizes, int n_in,
                              void* d_out, int out_size, void* d_ws, size_t ws_size,
                              hipStream_t stream) {
    const float* xyz1 = (const float*)d_in[0];
    const float* xyz2 = (const float*)d_in[1];
    float* out = (float*)d_out;

    // out := huge positive float so uint atomicMin always wins
    hipMemsetAsync(d_out, 0x7f, (size_t)out_size * sizeof(float), stream);

    // ws: 8 half8 arrays (16 B/point each) + sqArr (2*TOTAL floats)
    const size_t need = (size_t)TOTAL * 16 * 8 + (size_t)2 * TOTAL * 4;
    if (ws_size >= need &&
        in_sizes[0] == TOTAL * 3 && in_sizes[1] == TOTAL * 3) {
        char* w = (char*)d_ws;
        half8* Qlo1 = (half8*)(w);
        half8* Qhi1 = (half8*)(w + (size_t)TOTAL * 16 * 1);
        half8* Clo1 = (half8*)(w + (size_t)TOTAL * 16 * 2);
        half8* Chi1 = (half8*)(w + (size_t)TOTAL * 16 * 3);
        half8* Qlo2 = (half8*)(w + (size_t)TOTAL * 16 * 4);
        half8* Qhi2 = (half8*)(w + (size_t)TOTAL * 16 * 5);
        half8* Clo2 = (half8*)(w + (size_t)TOTAL * 16 * 6);
        half8* Chi2 = (half8*)(w + (size_t)TOTAL * 16 * 7);
        float* sqA  = (float*)(w + (size_t)TOTAL * 16 * 8);

        chamfer_prep<<<TOTAL / 256, 256, 0, stream>>>(
            xyz1, xyz2, Qlo1, Qhi1, Clo1, Chi1, Qlo2, Qhi2, Clo2, Chi2, sqA);
        dim3 grid(NPTS / ROWS_BLOCK, COL_SPLITS, 2 * BATCH);  // 16 x 2 x 16
        chamfer_mfma<<<grid, 256, 0, stream>>>(
            Qlo1, Qhi1, Clo1, Chi1, Qlo2, Qhi2, Clo2, Chi2, out);
        chamfer_fix<<<(2 * TOTAL) / 256, 256, 0, stream>>>(out, sqA);
    } else {
        dim3 grid(NPTS / FB_QB, NPTS / FB_CT, 2 * BATCH);
        chamfer_valu<<<grid, FB_BLOCK, 0, stream>>>(
            xyz1, xyz2, out, BATCH, NPTS, NPTS);
    }
}

// Round 7
// 202.731 us; speedup vs baseline: 5.0972x; 5.0972x over previous
//
#include <hip/hip_runtime.h>
#include <math.h>

// Chamfer distance on MI355X (gfx950) via f16-split MFMA, two one-directional
// passes in a single kernel.  B=8, N=M=8192, fp32.
// out = concat(dist1[B*N], dist2[B*M]).
//
// Per direction: U[n,m] = |c_m|^2 - 2 q_n.c_m + 64, min over m -> dist partial.
// v_mfma_f32_32x32x16_f16 K-slots (f16-split of the fp32 expansion):
//   k0..2: qh*ch   k3..5: qh*cl   k6..8: ql*ch   k9,10: 1*sq_hi,1*sq_lo
//   k11: 1*64 (bias keeps U>0 so uint atomicMin is order-preserving)
// Fix-up: out[i] = max(min - 64 + |q_i|^2, 0).
//
// R7 vs R6 post-mortem: R6 spilled (WRITE_SIZE 3 GB of scratch — mm[4][16] +
// dual d0/d1 needed ~154 VGPRs, compiled at 128).  R7 halves live state:
// RT_PER_WAVE=2 (a=8, mm=32 regs) and single col-tile in flight (one 16-reg
// d).  COL_SPLITS=4 restores parallelism: 2048 blocks = 8 blocks/CU.
//
// Fragment layouts (verified R5/R6 end-to-end, absmax ~1e-3 == VALU kernel):
// A[m=lane&31][k=(lane>>5)*8+j], B mirrored,
// C/D col=lane&31, row=(reg&3)+8*(reg>>2)+4*(lane>>5).

typedef __attribute__((ext_vector_type(8)))  _Float16 half8;
typedef __attribute__((ext_vector_type(16))) float    floatx16;

#define NPTS  8192
#define BATCH 8
#define TOTAL (NPTS * BATCH)

#define RT_PER_WAVE 2                         // 2 row-tiles = 64 rows / wave
#define ROWS_BLOCK  (4 * 32 * RT_PER_WAVE)    // 256 rows / block (4 waves)
#define COL_SPLITS  4
#define COLS_BLOCK  (NPTS / COL_SPLITS)       // 2048 cols / block
#define CHUNK_TILES 8                         // 256 cols staged per chunk
#define CHUNK_COLS  (CHUNK_TILES * 32)
#define CHUNK_RECS  (CHUNK_TILES * 64)        // lo+hi records (float4 each)
#define NCHUNK      (COLS_BLOCK / CHUNK_COLS) // 8

// ---------------- prep: query-form and candidate-form operand records -------
__global__ __launch_bounds__(256) void chamfer_prep(
    const float* __restrict__ xyz1, const float* __restrict__ xyz2,
    half8* __restrict__ Qlo1, half8* __restrict__ Qhi1,
    half8* __restrict__ Clo1, half8* __restrict__ Chi1,
    half8* __restrict__ Qlo2, half8* __restrict__ Qhi2,
    half8* __restrict__ Clo2, half8* __restrict__ Chi2,
    float* __restrict__ sqArr)
{
    const int p = blockIdx.x * 256 + threadIdx.x;
    if (p >= TOTAL) return;
    const _Float16 ONE = (_Float16)1.0f, ZERO = (_Float16)0.0f;

    for (int s = 0; s < 2; ++s) {
        const float* src = s ? xyz2 : xyz1;
        const float x = src[3*p+0], y = src[3*p+1], z = src[3*p+2];
        const float sq = fmaf(x, x, fmaf(y, y, z * z));

        // query form: k0-2=qh, k3-5=qh, k6-8=ql, k9-11=1
        _Float16 hx=(_Float16)x, hy=(_Float16)y, hz=(_Float16)z;
        _Float16 lx=(_Float16)(x-(float)hx), ly=(_Float16)(y-(float)hy),
                 lz=(_Float16)(z-(float)hz);
        half8 qlo; qlo[0]=hx; qlo[1]=hy; qlo[2]=hz; qlo[3]=hx; qlo[4]=hy;
                   qlo[5]=hz; qlo[6]=lx; qlo[7]=ly;
        half8 qhi; qhi[0]=lz; qhi[1]=ONE; qhi[2]=ONE; qhi[3]=ONE;
                   qhi[4]=ZERO; qhi[5]=ZERO; qhi[6]=ZERO; qhi[7]=ZERO;

        // candidate form (v=-2c): k0-2=ch, k3-5=cl, k6-8=ch, k9=sqh,k10=sql,k11=64
        const float vx=-2.f*x, vy=-2.f*y, vz=-2.f*z;
        _Float16 cx=(_Float16)vx, cy=(_Float16)vy, cz=(_Float16)vz;
        _Float16 dx=(_Float16)(vx-(float)cx), dy=(_Float16)(vy-(float)cy),
                 dz=(_Float16)(vz-(float)cz);
        _Float16 sh=(_Float16)sq, sl=(_Float16)(sq-(float)sh);
        half8 clo; clo[0]=cx; clo[1]=cy; clo[2]=cz; clo[3]=dx; clo[4]=dy;
                   clo[5]=dz; clo[6]=cx; clo[7]=cy;
        half8 chi; chi[0]=cz; chi[1]=sh; chi[2]=sl; chi[3]=(_Float16)64.0f;
                   chi[4]=ZERO; chi[5]=ZERO; chi[6]=ZERO; chi[7]=ZERO;

        if (s == 0) { Qlo1[p]=qlo; Qhi1[p]=qhi; Clo1[p]=clo; Chi1[p]=chi;
                      sqArr[p] = sq; }
        else        { Qlo2[p]=qlo; Qhi2[p]=qhi; Clo2[p]=clo; Chi2[p]=chi;
                      sqArr[TOTAL + p] = sq; }
    }
}

// ---------------- main: one-directional MFMA min scan -----------------------
// grid = (NPTS/256, COL_SPLITS, 2*BATCH) = (32, 4, 16) = 2048 blocks
__global__ __launch_bounds__(256, 2) void chamfer_mfma(
    const half8* __restrict__ Qlo1, const half8* __restrict__ Qhi1,
    const half8* __restrict__ Clo1, const half8* __restrict__ Chi1,
    const half8* __restrict__ Qlo2, const half8* __restrict__ Qhi2,
    const half8* __restrict__ Clo2, const half8* __restrict__ Chi2,
    float* __restrict__ out)
{
    const int zb   = blockIdx.z;
    const int dir  = zb >> 3;
    const int b    = zb & 7;
    const int tid  = threadIdx.x;
    const int lane = tid & 63, wave = tid >> 6;
    const int lm   = lane & 31;
    const bool hi  = lane >= 32;

    const half8 *Qlo, *Qhi, *Clo, *Chi; float* o;
    if (dir == 0) { Qlo=Qlo1; Qhi=Qhi1; Clo=Clo2; Chi=Chi2;
                    o = out + (size_t)b * NPTS; }
    else          { Qlo=Qlo2; Qhi=Qhi2; Clo=Clo1; Chi=Chi1;
                    o = out + (size_t)TOTAL + (size_t)b * NPTS; }

    __shared__ float4 sb[2][CHUNK_RECS];   // 2 x 8 KB double buffer

    // ---- A fragments: 2 row-tiles per wave, held in registers ----
    const int row_base = blockIdx.x * ROWS_BLOCK + wave * (RT_PER_WAVE * 32);
    const half8* Aarr = hi ? Qhi : Qlo;
    half8 a[RT_PER_WAVE];
#pragma unroll
    for (int rt = 0; rt < RT_PER_WAVE; ++rt)
        a[rt] = Aarr[(size_t)b * NPTS + row_base + rt * 32 + lm];

    float mm[RT_PER_WAVE][16];
#pragma unroll
    for (int rt = 0; rt < RT_PER_WAVE; ++rt)
#pragma unroll
        for (int r = 0; r < 16; ++r) mm[rt][r] = 3.0e38f;

    floatx16 zacc;
#pragma unroll
    for (int r = 0; r < 16; ++r) zacc[r] = 0.0f;

    const int col_base = blockIdx.y * COLS_BLOCK;
    const float4* gClo = (const float4*)(Clo + (size_t)b * NPTS);
    const float4* gChi = (const float4*)(Chi + (size_t)b * NPTS);

    // ---- stage chunk 0 (thread tid handles column col_base + tid) ----
    {
        const int src = col_base + tid;
        const int dst = (tid >> 5) * 64 + (tid & 31);
        sb[0][dst]      = gClo[src];
        sb[0][dst + 32] = gChi[src];
    }
    __syncthreads();

    const int boff = (hi ? 32 : 0) + lm;
    for (int c = 0; c < NCHUNK; ++c) {
        float4 n0, n1;
        if (c + 1 < NCHUNK) {                 // register prefetch of next chunk
            const int src = col_base + (c + 1) * CHUNK_COLS + tid;
            n0 = gClo[src];
            n1 = gChi[src];
        }
        const int cur = c & 1;
#pragma unroll
        for (int pt = 0; pt < CHUNK_TILES; ++pt) {
            const half8 bf = *(const half8*)&sb[cur][pt * 64 + boff];
#pragma unroll
            for (int rt = 0; rt < RT_PER_WAVE; ++rt) {
                floatx16 d = __builtin_amdgcn_mfma_f32_32x32x16_f16(a[rt], bf, zacc, 0, 0, 0);
#pragma unroll
                for (int r = 0; r < 16; ++r)
                    mm[rt][r] = fminf(mm[rt][r], d[r]);
            }
        }
        if (c + 1 < NCHUNK) {
            const int dst = (tid >> 5) * 64 + (tid & 31);
            sb[1 - cur][dst]      = n0;
            sb[1 - cur][dst + 32] = n1;
            __syncthreads();
        }
    }

    // ---- epilogue: 32-lane min reduce per row, merge via uint atomicMin ----
#pragma unroll
    for (int rt = 0; rt < RT_PER_WAVE; ++rt)
#pragma unroll
        for (int r = 0; r < 16; ++r) {
            float v = mm[rt][r];
            v = fminf(v, __shfl_xor(v, 1));
            v = fminf(v, __shfl_xor(v, 2));
            v = fminf(v, __shfl_xor(v, 4));
            v = fminf(v, __shfl_xor(v, 8));
            v = fminf(v, __shfl_xor(v, 16));
            if (lm == 0) {
                const int rit = (r & 3) + 8 * (r >> 2) + (hi ? 4 : 0);
                atomicMin((unsigned*)(o + row_base + rt * 32 + rit),
                          __float_as_uint(v));
            }
        }
}

// ---------------- fix-up: un-bias, add |q|^2, clamp -------------------------
__global__ __launch_bounds__(256) void chamfer_fix(
    float* __restrict__ out, const float* __restrict__ sqArr)
{
    const int i = blockIdx.x * 256 + threadIdx.x;
    if (i < 2 * TOTAL) out[i] = fmaxf(out[i] - 64.0f + sqArr[i], 0.0f);
}

// ---------------- fallback (R2 VALU kernel, if ws too small) ----------------
#define FB_BLOCK 256
#define FB_Q 8
#define FB_QB (FB_BLOCK * FB_Q)
#define FB_CT 256
__global__ __launch_bounds__(FB_BLOCK, 8) void chamfer_valu(
    const float* __restrict__ xyz1, const float* __restrict__ xyz2,
    float* __restrict__ out, int B, int N, int M)
{
    const int z = blockIdx.z, dir = z / B, b = z % B;
    const float* qp; const float* cp; float* o; int Nq, Nc;
    if (dir == 0) { qp = xyz1 + (size_t)b*N*3; cp = xyz2 + (size_t)b*M*3;
                    o = out + (size_t)b*N; Nq = N; Nc = M; }
    else          { qp = xyz2 + (size_t)b*M*3; cp = xyz1 + (size_t)b*N*3;
                    o = out + (size_t)B*N + (size_t)b*M; Nq = M; Nc = N; }
    __shared__ float4 sc[FB_CT];
    const int c0 = blockIdx.y * FB_CT;
    for (int i = threadIdx.x; i < FB_CT; i += FB_BLOCK) {
        const int j = c0 + i;
        float x=0,y=0,zz=0,sq=3.0e38f;
        if (j < Nc) { x=cp[3*j]; y=cp[3*j+1]; zz=cp[3*j+2]; sq=x*x+y*y+zz*zz; }
        sc[i] = make_float4(-2.f*x, -2.f*y, -2.f*zz, sq);
    }
    __syncthreads();
    const int n0 = blockIdx.x * FB_QB + threadIdx.x;
    float qx[FB_Q], qy[FB_Q], qz[FB_Q], mm[FB_Q];
#pragma unroll
    for (int q = 0; q < FB_Q; ++q) {
        const int n = n0 + q*FB_BLOCK; float x=0,y=0,zz=0;
        if (n < Nq) { x=qp[3*n]; y=qp[3*n+1]; zz=qp[3*n+2]; }
        qx[q]=x; qy[q]=y; qz[q]=zz; mm[q]=3.0e38f;
    }
#pragma unroll 2
    for (int j = 0; j < FB_CT; j += 2) {
        const float4 ca = sc[j], cb = sc[j+1];
#pragma unroll
        for (int q = 0; q < FB_Q; ++q) {
            float t0 = fmaf(qx[q],ca.x,ca.w); t0=fmaf(qy[q],ca.y,t0); t0=fmaf(qz[q],ca.z,t0);
            float t1 = fmaf(qx[q],cb.x,cb.w); t1=fmaf(qy[q],cb.y,t1); t1=fmaf(qz[q],cb.z,t1);
            mm[q] = fminf(fminf(t0,t1), mm[q]);
        }
    }
#pragma unroll
    for (int q = 0; q < FB_Q; ++q) {
        const int n = n0 + q*FB_BLOCK;
        if (n < Nq) {
            float s = qx[q]*qx[q]; s=fmaf(qy[q],qy[q],s); s=fmaf(qz[q],qz[q],s);
            atomicMin((unsigned*)(o+n), __float_as_uint(fmaxf(s+mm[q],0.f)));
        }
    }
}

extern "C" void kernel_launch(void* const* d_in, const int* in_sizes, int n_in,
                              void* d_out, int out_size, void* d_ws, size_t ws_size,
                              hipStream_t stream) {
    const float* xyz1 = (const float*)d_in[0];
    const float* xyz2 = (const float*)d_in[1];
    float* out = (float*)d_out;

    // out := huge positive float so uint atomicMin always wins
    hipMemsetAsync(d_out, 0x7f, (size_t)out_size * sizeof(float), stream);

    // ws: 8 half8 arrays (16 B/point each) + sqArr (2*TOTAL floats)
    const size_t need = (size_t)TOTAL * 16 * 8 + (size_t)2 * TOTAL * 4;
    if (ws_size >= need &&
        in_sizes[0] == TOTAL * 3 && in_sizes[1] == TOTAL * 3) {
        char* w = (char*)d_ws;
        half8* Qlo1 = (half8*)(w);
        half8* Qhi1 = (half8*)(w + (size_t)TOTAL * 16 * 1);
        half8* Clo1 = (half8*)(w + (size_t)TOTAL * 16 * 2);
        half8* Chi1 = (half8*)(w + (size_t)TOTAL * 16 * 3);
        half8* Qlo2 = (half8*)(w + (size_t)TOTAL * 16 * 4);
        half8* Qhi2 = (half8*)(w + (size_t)TOTAL * 16 * 5);
        half8* Clo2 = (half8*)(w + (size_t)TOTAL * 16 * 6);
        half8* Chi2 = (half8*)(w + (size_t)TOTAL * 16 * 7);
        float* sqA  = (float*)(w + (size_t)TOTAL * 16 * 8);

        chamfer_prep<<<TOTAL / 256, 256, 0, stream>>>(
            xyz1, xyz2, Qlo1, Qhi1, Clo1, Chi1, Qlo2, Qhi2, Clo2, Chi2, sqA);
        dim3 grid(NPTS / ROWS_BLOCK, COL_SPLITS, 2 * BATCH);  // 32 x 4 x 16
        chamfer_mfma<<<grid, 256, 0, stream>>>(
            Qlo1, Qhi1, Clo1, Chi1, Qlo2, Qhi2, Clo2, Chi2, out);
        chamfer_fix<<<(2 * TOTAL) / 256, 256, 0, stream>>>(out, sqA);
    } else {
        dim3 grid(NPTS / FB_QB, NPTS / FB_CT, 2 * BATCH);
        chamfer_valu<<<grid, FB_BLOCK, 0, stream>>>(
            xyz1, xyz2, out, BATCH, NPTS, NPTS);
    }
}